// Round 2
// baseline (253.029 us; speedup 1.0000x reference)
//
#include <hip/hip_runtime.h>

#define DIMN 192
#define SD (DIMN * DIMN)
#define TY 16                 // output tile h
#define TX 16                 // output tile w
#define RY (TY + 8)           // halo rows
#define RX (TX + 8)           // halo cols
#define NT (DIMN / TY)        // 12 tiles per spatial dim
#define ND 8                  // d-chunks
#define DCH (DIMN / ND)       // 24 outputs per chunk
#define NSL (DCH + 8)         // 32 input slices per chunk
#define NBLK (NT * NT * ND)   // 1152 blocks
#define WIN_F 729.0f

// ---------------------------------------------------------------------------
// Fully fused NCC: per block = 16x16 (h,w) tile x 24-deep d-chunk.
// Slide along d with a 9-deep per-thread VGPR ring of HW-box-summed values
// for the 5 channels {I, J, I^2, J^2, IJ}. No intermediate in HBM.
// ---------------------------------------------------------------------------
__global__ __launch_bounds__(256) void ncc_fused(const float* __restrict__ I,
                                                 const float* __restrict__ J,
                                                 double* __restrict__ partials) {
    __shared__ float si[RY][RX + 1];     // +1 pad: ~2-way max conflicts on 9-tap reads
    __shared__ float sj[RY][RX + 1];
    __shared__ __align__(16) float wtmp[RY * TX * 8];  // 8-float slots, bit-4 XOR swizzle
    __shared__ double wred[4];

    const int bid = blockIdx.x;
    const int tw = bid % NT;
    const int th = (bid / NT) % NT;
    const int td = bid / (NT * NT);
    const int h0 = th * TY;
    const int w0 = tw * TX;
    const int d0 = td * DCH;

    const int tid = threadIdx.x;
    const int tx = tid & 15;
    const int ty = tid >> 4;

    float ring[9][5];
#pragma unroll
    for (int k = 0; k < 9; k++)
#pragma unroll
        for (int q = 0; q < 5; q++) ring[k][q] = 0.f;
    float run[5] = {0.f, 0.f, 0.f, 0.f, 0.f};
    double acc = 0.0;

    for (int i = 0; i < NSL; i++) {
        const int s = d0 - 4 + i;
        const bool valid = (s >= 0) && (s < DIMN);   // block-uniform

        __syncthreads();   // prev iter's wsum readers done before si/sj overwrite
        if (valid) {
            const float* Ip = I + (size_t)s * SD;
            const float* Jp = J + (size_t)s * SD;
            for (int p = tid; p < RY * RX; p += 256) {
                const int r = p / RX;
                const int c = p - r * RX;
                const int hh = h0 - 4 + r;
                const int ww = w0 - 4 + c;
                const bool inb = ((unsigned)hh < DIMN) && ((unsigned)ww < DIMN);
                const int g = inb ? (hh * DIMN + ww) : 0;
                si[r][c] = inb ? Ip[g] : 0.f;
                sj[r][c] = inb ? Jp[g] : 0.f;
            }
        }
        __syncthreads();

        if (valid) {
            // W-pass: 24 rows x 16 output columns of 5-channel 9-tap sums
            for (int p = tid; p < RY * TX; p += 256) {
                const int r = p >> 4;
                const int c = p & 15;
                float s0 = 0.f, s1 = 0.f, s2 = 0.f, s3 = 0.f, s4 = 0.f;
#pragma unroll
                for (int k = 0; k < 9; k++) {
                    const float a = si[r][c + k];
                    const float b = sj[r][c + k];
                    s0 += a;
                    s1 += b;
                    s2 += a * a;
                    s3 += b * b;
                    s4 += a * b;
                }
                const int p6 = (r << 4) + c;
                const int f4i = (p6 << 3) + (c & 4);          // swizzled float4 slot
                *(float4*)&wtmp[f4i] = make_float4(s0, s1, s2, s3);
                wtmp[f4i ^ 4] = s4;                           // 5th channel, other half
            }
        }
        __syncthreads();

        float hw0 = 0.f, hw1 = 0.f, hw2 = 0.f, hw3 = 0.f, hw4 = 0.f;
        if (valid) {
            // H-pass: 9-tap column sum at this thread's (ty, tx)
#pragma unroll
            for (int k = 0; k < 9; k++) {
                const int p6 = ((ty + k) << 4) + tx;
                const int f4i = (p6 << 3) + (tx & 4);
                const float4 v = *(const float4*)&wtmp[f4i];
                hw0 += v.x;
                hw1 += v.y;
                hw2 += v.z;
                hw3 += v.w;
                hw4 += wtmp[f4i ^ 4];
            }
        }

        // d sliding window: run = sum of last 9 hw's (zeros outside)
        run[0] += hw0 - ring[0][0];
        run[1] += hw1 - ring[0][1];
        run[2] += hw2 - ring[0][2];
        run[3] += hw3 - ring[0][3];
        run[4] += hw4 - ring[0][4];

        if (i >= 8) {
            const float s0 = run[0], s1 = run[1], s2 = run[2], s3 = run[3], s4 = run[4];
            const float u_I = s0 / WIN_F;
            const float u_J = s1 / WIN_F;
            const float cross = s4 - u_J * s0 - u_I * s1 + u_I * u_J * WIN_F;
            const float I_var = s2 - 2.0f * u_I * s0 + u_I * u_I * WIN_F;
            const float J_var = s3 - 2.0f * u_J * s1 + u_J * u_J * WIN_F;
            const float cc = cross * cross / (I_var * J_var + 1e-5f);
            acc += (double)cc;
        }

        // shift ring (static indices -> VGPRs)
#pragma unroll
        for (int k = 0; k < 8; k++)
#pragma unroll
            for (int q = 0; q < 5; q++) ring[k][q] = ring[k + 1][q];
        ring[8][0] = hw0;
        ring[8][1] = hw1;
        ring[8][2] = hw2;
        ring[8][3] = hw3;
        ring[8][4] = hw4;
    }

    // block reduction (256 threads = 4 waves)
#pragma unroll
    for (int off = 32; off > 0; off >>= 1) acc += __shfl_down(acc, off, 64);
    if ((tid & 63) == 0) wred[tid >> 6] = acc;
    __syncthreads();
    if (tid == 0) partials[bid] = wred[0] + wred[1] + wred[2] + wred[3];
}

// ---------------------------------------------------------------------------
// Final reduction: NBLK doubles -> out[0] = -(mean cc)
// ---------------------------------------------------------------------------
__global__ void k_final(const double* __restrict__ partials, float* __restrict__ out) {
    __shared__ double wred[4];
    double acc = 0.0;
    for (int i = threadIdx.x; i < NBLK; i += 256) acc += partials[i];
#pragma unroll
    for (int off = 32; off > 0; off >>= 1) acc += __shfl_down(acc, off, 64);
    if ((threadIdx.x & 63) == 0) wred[threadIdx.x >> 6] = acc;
    __syncthreads();
    if (threadIdx.x == 0) {
        const double total = wred[0] + wred[1] + wred[2] + wred[3];
        out[0] = -(float)(total / (double)((size_t)DIMN * DIMN * DIMN));
    }
}

extern "C" void kernel_launch(void* const* d_in, const int* in_sizes, int n_in,
                              void* d_out, int out_size, void* d_ws, size_t ws_size,
                              hipStream_t stream) {
    const float* I = (const float*)d_in[0];   // y_true
    const float* J = (const float*)d_in[1];   // y_pred
    double* partials = (double*)d_ws;
    float* out = (float*)d_out;

    hipLaunchKernelGGL(ncc_fused, dim3(NBLK), dim3(256), 0, stream, I, J, partials);
    hipLaunchKernelGGL(k_final, dim3(1), dim3(256), 0, stream, partials, out);
}

// Round 3
// 211.101 us; speedup vs baseline: 1.1986x; 1.1986x over previous
//
#include <hip/hip_runtime.h>
#include <hip/hip_fp16.h>

#define DIMN 192
#define SD (DIMN * DIMN)
#define CS (DIMN * DIMN * DIMN)
#define WIN_F 729.0f

#define TY1 48                 // K1 h-band
#define NB1 (DIMN / TY1)       // 4 bands
#define NROW (TY1 + 8)         // 56 rows walked per band

#define DCH2 48                // K2 d-chunk
#define ND2 (DIMN / DCH2)      // 4 chunks
#define HWB (SD / 256)         // 144 hw-blocks
#define NPART (ND2 * HWB)      // 576 partials

// ---------------------------------------------------------------------------
// K1: W+H box sums per slice. Block = 192 threads (one full W row), walks 56
// h-rows of one 48-row band. LDS holds one (I,J)-interleaved row (double-
// buffered, zero-padded +-4). H-window = fully unrolled i%9 register ring
// (static indices, no shifts). Emits 5 channels as f16 (pairs packed).
// ---------------------------------------------------------------------------
__global__ __launch_bounds__(192) void k1_wh(const float* __restrict__ I,
                                             const float* __restrict__ J,
                                             __half2* __restrict__ ch01,
                                             __half2* __restrict__ ch23,
                                             __half* __restrict__ ch4) {
    __shared__ float2 srow[2][DIMN + 8];
    const int s  = blockIdx.x / NB1;
    const int h0 = (blockIdx.x % NB1) * TY1;
    const int w  = threadIdx.x;

    if (w < 4) {   // zero pads, written once
        srow[0][w] = make_float2(0.f, 0.f);
        srow[1][w] = make_float2(0.f, 0.f);
        srow[0][DIMN + 4 + w] = make_float2(0.f, 0.f);
        srow[1][DIMN + 4 + w] = make_float2(0.f, 0.f);
    }

    const float* Ip = I + (size_t)s * SD + w;
    const float* Jp = J + (size_t)s * SD + w;

    float ring[9][5];
#pragma unroll
    for (int k = 0; k < 9; k++)
#pragma unroll
        for (int q = 0; q < 5; q++) ring[k][q] = 0.f;
    float run[5] = {0.f, 0.f, 0.f, 0.f, 0.f};

    // prefetch first row (rr = h0-4)
    const int rr0 = h0 - 4;
    float iv = 0.f, jv = 0.f;
    if ((unsigned)rr0 < DIMN) { iv = Ip[rr0 * DIMN]; jv = Jp[rr0 * DIMN]; }
    __syncthreads();   // pads visible

#pragma unroll
    for (int i = 0; i < NROW; ++i) {
        srow[i & 1][4 + w] = make_float2(iv, jv);
        // prefetch next row (overlaps with compute below)
        const int rn = h0 - 3 + i;
        float ivn = 0.f, jvn = 0.f;
        if (i + 1 < NROW && (unsigned)rn < DIMN) { ivn = Ip[rn * DIMN]; jvn = Jp[rn * DIMN]; }
        __syncthreads();

        float s0 = 0.f, s1 = 0.f, s2 = 0.f, s3 = 0.f, s4 = 0.f;
#pragma unroll
        for (int k = 0; k < 9; k++) {
            const float2 ab = srow[i & 1][w + k];
            s0 += ab.x;
            s1 += ab.y;
            s2 += ab.x * ab.x;
            s3 += ab.y * ab.y;
            s4 += ab.x * ab.y;
        }
        const int m = i % 9;   // static after unroll
        run[0] += s0 - ring[m][0]; ring[m][0] = s0;
        run[1] += s1 - ring[m][1]; ring[m][1] = s1;
        run[2] += s2 - ring[m][2]; ring[m][2] = s2;
        run[3] += s3 - ring[m][3]; ring[m][3] = s3;
        run[4] += s4 - ring[m][4]; ring[m][4] = s4;

        if (i >= 8) {
            const int ho = h0 + i - 8;
            const size_t o = (size_t)s * SD + (size_t)ho * DIMN + w;
            ch01[o] = __floats2half2_rn(run[0], run[1]);
            ch23[o] = __floats2half2_rn(run[2], run[3]);
            ch4[o]  = __float2half_rn(run[4]);
        }
        iv = ivn;
        jv = jvn;
    }
}

// ---------------------------------------------------------------------------
// K2: D-pass + cc + partial reduce. Thread per (h,w) point, walks 56 d-slices
// of one 48-chunk with the same unrolled i%9 ring. Coalesced f16 loads.
// ---------------------------------------------------------------------------
__global__ __launch_bounds__(256) void k2_dcc(const __half2* __restrict__ ch01,
                                              const __half2* __restrict__ ch23,
                                              const __half* __restrict__ ch4,
                                              double* __restrict__ partials) {
    const int chunk = blockIdx.x / HWB;
    const int hw = (blockIdx.x % HWB) * 256 + threadIdx.x;
    const int d0 = chunk * DCH2;

    float ring[9][5];
#pragma unroll
    for (int k = 0; k < 9; k++)
#pragma unroll
        for (int q = 0; q < 5; q++) ring[k][q] = 0.f;
    float run[5] = {0.f, 0.f, 0.f, 0.f, 0.f};
    double acc = 0.0;

#pragma unroll
    for (int i = 0; i < DCH2 + 8; ++i) {
        const int ds = d0 - 4 + i;                 // block-uniform predicate
        float a0 = 0.f, a1 = 0.f, a2 = 0.f, a3 = 0.f, a4 = 0.f;
        if ((unsigned)ds < DIMN) {
            const size_t o = (size_t)ds * SD + hw;
            const float2 f01 = __half22float2(ch01[o]);
            const float2 f23 = __half22float2(ch23[o]);
            a0 = f01.x; a1 = f01.y;
            a2 = f23.x; a3 = f23.y;
            a4 = __half2float(ch4[o]);
        }
        const int m = i % 9;
        run[0] += a0 - ring[m][0]; ring[m][0] = a0;
        run[1] += a1 - ring[m][1]; ring[m][1] = a1;
        run[2] += a2 - ring[m][2]; ring[m][2] = a2;
        run[3] += a3 - ring[m][3]; ring[m][3] = a3;
        run[4] += a4 - ring[m][4]; ring[m][4] = a4;

        if (i >= 8) {
            const float s0 = run[0], s1 = run[1], s2 = run[2], s3 = run[3], s4 = run[4];
            const float u_I = s0 / WIN_F;
            const float u_J = s1 / WIN_F;
            const float cross = s4 - u_J * s0 - u_I * s1 + u_I * u_J * WIN_F;
            const float I_var = s2 - 2.0f * u_I * s0 + u_I * u_I * WIN_F;
            const float J_var = s3 - 2.0f * u_J * s1 + u_J * u_J * WIN_F;
            acc += (double)(cross * cross / (I_var * J_var + 1e-5f));
        }
    }

    __shared__ double wred[4];
#pragma unroll
    for (int off = 32; off > 0; off >>= 1) acc += __shfl_down(acc, off, 64);
    if ((threadIdx.x & 63) == 0) wred[threadIdx.x >> 6] = acc;
    __syncthreads();
    if (threadIdx.x == 0) partials[blockIdx.x] = wred[0] + wred[1] + wred[2] + wred[3];
}

// ---------------------------------------------------------------------------
// K3: final reduce -> out[0] = -(mean cc)
// ---------------------------------------------------------------------------
__global__ void k_final(const double* __restrict__ partials, float* __restrict__ out) {
    __shared__ double wred[4];
    double acc = 0.0;
    for (int i = threadIdx.x; i < NPART; i += 256) acc += partials[i];
#pragma unroll
    for (int off = 32; off > 0; off >>= 1) acc += __shfl_down(acc, off, 64);
    if ((threadIdx.x & 63) == 0) wred[threadIdx.x >> 6] = acc;
    __syncthreads();
    if (threadIdx.x == 0) {
        const double total = wred[0] + wred[1] + wred[2] + wred[3];
        out[0] = -(float)(total / (double)CS);
    }
}

extern "C" void kernel_launch(void* const* d_in, const int* in_sizes, int n_in,
                              void* d_out, int out_size, void* d_ws, size_t ws_size,
                              hipStream_t stream) {
    const float* I = (const float*)d_in[0];   // y_true
    const float* J = (const float*)d_in[1];   // y_pred
    char* ws = (char*)d_ws;
    __half2* ch01 = (__half2*)ws;                              // CS * 4 B
    __half2* ch23 = (__half2*)(ws + (size_t)CS * 4);           // CS * 4 B
    __half*  ch4  = (__half*)(ws + (size_t)CS * 8);            // CS * 2 B
    double* partials = (double*)(ws + (size_t)CS * 10);        // NPART * 8 B
    float* out = (float*)d_out;

    hipLaunchKernelGGL(k1_wh, dim3(DIMN * NB1), dim3(DIMN), 0, stream, I, J, ch01, ch23, ch4);
    hipLaunchKernelGGL(k2_dcc, dim3(ND2 * HWB), dim3(256), 0, stream, ch01, ch23, ch4, partials);
    hipLaunchKernelGGL(k_final, dim3(1), dim3(256), 0, stream, partials, out);
}

// Round 5
// 189.597 us; speedup vs baseline: 1.3346x; 1.1134x over previous
//
#include <hip/hip_runtime.h>
#include <hip/hip_fp16.h>

#define DIMN 192
#define SD (DIMN * DIMN)             // 36864
#define CS (DIMN * DIMN * DIMN)      // 7077888
#define WIN_F 729.0f
#define NPART (DIMN * 4)             // 768 partials from K3

typedef unsigned int uint32;

__device__ __forceinline__ float2 up32(uint32 u) {
    __half2 h = *(__half2*)&u;
    return __half22float2(h);
}
__device__ __forceinline__ uint32 pk32(float x, float y) {
    __half2 h = __floats2half2_rn(x, y);
    return *(uint32*)&h;
}

// ---------------------------------------------------------------------------
// K1: W-pass. One block per (d,h) row, 192 threads. LDS-staged row, 9-tap
// zero-padded sums of {I, J, I*I, J*J, I*J}, emitted as f16.
// ---------------------------------------------------------------------------
__global__ __launch_bounds__(192) void k1_w(const float* __restrict__ I,
                                            const float* __restrict__ J,
                                            __half2* __restrict__ s01,
                                            __half2* __restrict__ s23,
                                            __half* __restrict__ s4) {
    __shared__ float si[DIMN];
    __shared__ float sj[DIMN];
    const int bid = blockIdx.x;
    const int base = bid * DIMN;     // (d*192 + h) * 192
    const int w = threadIdx.x;
    si[w] = I[base + w];
    sj[w] = J[base + w];
    __syncthreads();
    float t0 = 0.f, t1 = 0.f, t2 = 0.f, t3 = 0.f, t4 = 0.f;
#pragma unroll
    for (int k = -4; k <= 4; k++) {
        const int ww = w + k;
        if ((unsigned)ww < DIMN) {
            const float a = si[ww], b = sj[ww];
            t0 += a;
            t1 += b;
            t2 += a * a;
            t3 += b * b;
            t4 += a * b;
        }
    }
    s01[base + w] = __floats2half2_rn(t0, t1);
    s23[base + w] = __floats2half2_rn(t2, t3);
    s4[base + w] = __float2half_rn(t4);
}

// ---------------------------------------------------------------------------
// K2: H-pass, src -> dst (not in place, so h is chunked x2 for parallelism).
// 960 blocks x 192 threads. Thread walks 96 h-rows at one (array, d, col)
// with a 9-deep register shift ring of float2 (u32 = half2 elements).
//   bid <  384: ch01, b=bid,     chunk=b&1, d=b>>1, col=tid, stride=192
//   bid <  768: ch23, b=bid-384, same decode
//   bid >= 768: ch4 as u32 pairs: b=bid-768, bb=b>>1, d=2*bb+(tid>=96),
//               col=tid%96, stride=96
// ---------------------------------------------------------------------------
__global__ __launch_bounds__(192) void k2_h(const uint32* __restrict__ s01,
                                            const uint32* __restrict__ s23,
                                            const uint32* __restrict__ s4,
                                            uint32* __restrict__ d01,
                                            uint32* __restrict__ d23,
                                            uint32* __restrict__ d4) {
    const int bid = blockIdx.x;
    const int tid = threadIdx.x;
    const uint32* sp;
    uint32* dp;
    int stride, h0;
    if (bid < 768) {
        const int b = (bid < 384) ? bid : (bid - 384);   // FIXED: was bid & 383
        const int chunk = b & 1;
        const int d = b >> 1;
        const int off = d * SD + tid;
        stride = DIMN;
        h0 = chunk * 96;
        if (bid < 384) { sp = s01 + off; dp = d01 + off; }
        else           { sp = s23 + off; dp = d23 + off; }
    } else {
        const int b = bid - 768;
        const int chunk = b & 1;
        const int bb = b >> 1;
        const int d = 2 * bb + (tid >= 96 ? 1 : 0);
        const int col = (tid >= 96) ? tid - 96 : tid;
        const int off = d * (SD / 2) + col;
        stride = 96;
        h0 = chunk * 96;
        sp = s4 + off;
        dp = d4 + off;
    }

    float2 win[9];
    float2 run = make_float2(0.f, 0.f);
#pragma unroll
    for (int k = 0; k < 9; k++) {
        const int hh = h0 - 4 + k;
        float2 v = make_float2(0.f, 0.f);
        if (hh >= 0) v = up32(sp[hh * stride]);   // hh <= h0+4 <= 100 < 192 always
        win[k] = v;
        run.x += v.x;
        run.y += v.y;
    }
    for (int h = h0; h < h0 + 96; h++) {
        dp[h * stride] = pk32(run.x, run.y);
        const int hn = h + 5;
        float2 v = make_float2(0.f, 0.f);
        if (hn < DIMN) v = up32(sp[hn * stride]);
        run.x += v.x - win[0].x;
        run.y += v.y - win[0].y;
#pragma unroll
        for (int k = 0; k < 8; k++) win[k] = win[k + 1];
        win[8] = v;
    }
}

// ---------------------------------------------------------------------------
// K3: D-pass + cc + partial reduce. 768 blocks (192 h x 4 d-chunks) x 192
// threads (w). Running 5-channel sum along d maintained by re-reading the
// +5 / -4 taps (dst buffers are read-only here; L3-resident). cc in the
// reference's f32 order; double accumulation.
// ---------------------------------------------------------------------------
__global__ __launch_bounds__(192) void k3_dcc(const uint32* __restrict__ d01,
                                              const uint32* __restrict__ d23,
                                              const __half* __restrict__ d4,
                                              double* __restrict__ partials) {
    const int bid = blockIdx.x;
    const int h = bid >> 2;
    const int d0 = (bid & 3) * 48;
    const int w = threadIdx.x;
    const uint32* p01 = d01 + h * DIMN + w;
    const uint32* p23 = d23 + h * DIMN + w;
    const __half* p4 = d4 + h * DIMN + w;

    float r0 = 0.f, r1 = 0.f, r2 = 0.f, r3 = 0.f, r4 = 0.f;
#pragma unroll
    for (int k = 0; k < 9; k++) {
        const int dd = d0 - 4 + k;
        if ((unsigned)dd < DIMN) {
            const float2 a = up32(p01[dd * SD]);
            const float2 b = up32(p23[dd * SD]);
            r0 += a.x;
            r1 += a.y;
            r2 += b.x;
            r3 += b.y;
            r4 += __half2float(p4[dd * SD]);
        }
    }

    double acc = 0.0;
    for (int d = d0; d < d0 + 48; d++) {
        const float u_I = r0 / WIN_F;
        const float u_J = r1 / WIN_F;
        const float cross = r4 - u_J * r0 - u_I * r1 + u_I * u_J * WIN_F;
        const float I_var = r2 - 2.0f * u_I * r0 + u_I * u_I * WIN_F;
        const float J_var = r3 - 2.0f * u_J * r1 + u_J * u_J * WIN_F;
        acc += (double)(cross * cross / (I_var * J_var + 1e-5f));

        const int da = d + 5, ds = d - 4;   // block-uniform predicates
        if (da < DIMN) {
            const float2 a = up32(p01[da * SD]);
            const float2 b = up32(p23[da * SD]);
            r0 += a.x; r1 += a.y; r2 += b.x; r3 += b.y;
            r4 += __half2float(p4[da * SD]);
        }
        if (ds >= 0) {
            const float2 a = up32(p01[ds * SD]);
            const float2 b = up32(p23[ds * SD]);
            r0 -= a.x; r1 -= a.y; r2 -= b.x; r3 -= b.y;
            r4 -= __half2float(p4[ds * SD]);
        }
    }

    __shared__ double wred[3];
#pragma unroll
    for (int off = 32; off > 0; off >>= 1) acc += __shfl_down(acc, off, 64);
    if ((threadIdx.x & 63) == 0) wred[threadIdx.x >> 6] = acc;
    __syncthreads();
    if (threadIdx.x == 0) partials[bid] = wred[0] + wred[1] + wred[2];
}

// ---------------------------------------------------------------------------
// K4: final reduce -> out[0] = -(mean cc)
// ---------------------------------------------------------------------------
__global__ void k_final(const double* __restrict__ partials, float* __restrict__ out) {
    __shared__ double wred[4];
    double acc = 0.0;
    for (int i = threadIdx.x; i < NPART; i += 256) acc += partials[i];
#pragma unroll
    for (int off = 32; off > 0; off >>= 1) acc += __shfl_down(acc, off, 64);
    if ((threadIdx.x & 63) == 0) wred[threadIdx.x >> 6] = acc;
    __syncthreads();
    if (threadIdx.x == 0) {
        const double total = wred[0] + wred[1] + wred[2] + wred[3];
        out[0] = -(float)(total / (double)CS);
    }
}

extern "C" void kernel_launch(void* const* d_in, const int* in_sizes, int n_in,
                              void* d_out, int out_size, void* d_ws, size_t ws_size,
                              hipStream_t stream) {
    const float* I = (const float*)d_in[0];   // y_true
    const float* J = (const float*)d_in[1];   // y_pred
    char* ws = (char*)d_ws;
    // W-sum buffers (f16): s01 half2 (4B/pt), s23 half2, s4 half (2B/pt)
    __half2* s01 = (__half2*)(ws);
    __half2* s23 = (__half2*)(ws + (size_t)CS * 4);
    __half*  s4  = (__half*)(ws + (size_t)CS * 8);
    // H-sum buffers
    __half2* t01 = (__half2*)(ws + (size_t)CS * 10);
    __half2* t23 = (__half2*)(ws + (size_t)CS * 14);
    __half*  t4  = (__half*)(ws + (size_t)CS * 18);
    double* partials = (double*)(ws + (size_t)CS * 20);
    float* out = (float*)d_out;

    hipLaunchKernelGGL(k1_w, dim3(DIMN * DIMN), dim3(DIMN), 0, stream, I, J, s01, s23, s4);
    hipLaunchKernelGGL(k2_h, dim3(960), dim3(DIMN), 0, stream,
                       (const uint32*)s01, (const uint32*)s23, (const uint32*)s4,
                       (uint32*)t01, (uint32*)t23, (uint32*)t4);
    hipLaunchKernelGGL(k3_dcc, dim3(NPART), dim3(DIMN), 0, stream,
                       (const uint32*)t01, (const uint32*)t23, t4, partials);
    hipLaunchKernelGGL(k_final, dim3(1), dim3(256), 0, stream, partials, out);
}